// Round 16
// baseline (262.816 us; speedup 1.0000x reference)
//
#include <hip/hip_runtime.h>
#include <hip/hip_bf16.h>

typedef __hip_bfloat16 bf16;
__device__ __forceinline__ float b2f(bf16 v){ return __bfloat162float(v); }
__device__ __forceinline__ bf16 f2b(float v){ return __float2bfloat16(v); }

typedef __attribute__((ext_vector_type(8))) short frag_ab;   // 8 bf16 (4 VGPRs)
typedef __attribute__((ext_vector_type(4))) float frag_cd;   // 4 fp32 acc
typedef __attribute__((ext_vector_type(4))) short short4v;   // 8B

__device__ __forceinline__ frag_ab ld_frag_2xb64(const bf16* p){
  union { frag_ab f; short4v h[2]; } u;
  u.h[0] = *reinterpret_cast<const short4v*>(p);
  u.h[1] = *reinterpret_cast<const short4v*>(p+4);
  return u.f;
}

#define LLEN 3136
#define BATCH 2
#define NCHUNK 49
#define LC 64

// ---------------- fused: dwconv3x3+gelu (blocks 0..1023) | LayerNorm (blocks 1024..1135) ----------------
__global__ void k_front(const float* __restrict__ x, const float* __restrict__ dww,
                        const float* __restrict__ dwb, bf16* __restrict__ tmp,
                        const float* nhw_, const float* nhb_, const float* nvw_,
                        const float* nvb_, bf16* __restrict__ xln,
                        float* __restrict__ YMEAN){
  int blk = blockIdx.x;
  int tid = threadIdx.x;
  if (blk < 1024){
    // ---- depthwise conv 3x3 + gelu, 4-way spatial split ----
    int bc = blk & 255;            // b*128 + c
    int seg = blk >> 8;
    int c = bc & 127;
    if (bc == 0 && seg == 0 && tid < 256) YMEAN[tid] = 0.f;
    const float* xp = x + (size_t)bc*LLEN;
    float w[9];
    #pragma unroll
    for (int i=0;i<9;i++) w[i] = dww[c*9+i];
    float bias = dwb[c];
    int pstart = seg * 784;
    for (int p = pstart + tid; p < pstart + 784; p += 256){
      int i = p/56, j = p%56;
      float acc = bias;
      #pragma unroll
      for (int a=0;a<3;a++){
        int ii = i + a - 1;
        if (ii < 0 || ii >= 56) continue;
        #pragma unroll
        for (int bb=0;bb<3;bb++){
          int jj = j + bb - 1;
          if (jj < 0 || jj >= 56) continue;
          acc += w[a*3+bb] * xp[ii*56+jj];
        }
      }
      float g = 0.5f*acc*(1.0f + erff(acc*0.70710678118654752f));
      tmp[(size_t)bc*LLEN + p] = f2b(g);
    }
  } else {
    // ---- LayerNorm over C, both direction orderings ----
    int idx2 = blk - 1024;         // 0..111
    int h = idx2 % 56, b = idx2 / 56;
    __shared__ float sx[128][57];
    __shared__ float smean[56], srstd[56];
    __shared__ float wh[128], bh[128], wv_[128], bv_[128];
    if (tid < 128){ wh[tid]=nhw_[tid]; bh[tid]=nhb_[tid];
                    wv_[tid]=nvw_[tid]; bv_[tid]=nvb_[tid]; }
    for (int idx = tid; idx < 128*56; idx += 256){
      int c = idx / 56, w = idx % 56;
      sx[c][w] = x[((size_t)(b*128+c))*LLEN + h*56 + w];
    }
    __syncthreads();
    if (tid < 56){
      float s=0.f, s2=0.f;
      for (int c=0;c<128;c++){ float v = sx[c][tid]; s+=v; s2+=v*v; }
      float m = s*(1.f/128.f);
      float var = s2*(1.f/128.f) - m*m;
      smean[tid]=m; srstd[tid]=rsqrtf(var+1e-5f);
    }
    __syncthreads();
    bf16* outh = xln;
    bf16* outv = xln + (size_t)BATCH*LLEN*128;
    for (int idx = tid; idx < 56*128; idx += 256){
      int w = idx >> 7, c = idx & 127;
      float v = (sx[c][w]-smean[w])*srstd[w];
      outh[((size_t)b*LLEN + h*56 + w)*128 + c] = f2b(v*wh[c]+bh[c]);
      outv[((size_t)b*LLEN + w*56 + h)*128 + c] = f2b(v*wv_[c]+bv_[c]);
    }
  }
}

// ---------------- in_proj GEMM (MFMA bf16): 64-row tile, 2 n-tiles per block (A staged once) ----------------
__global__ void k_inproj(const bf16* __restrict__ xln, const float* __restrict__ hw,
                         const float* __restrict__ vw, bf16* __restrict__ XI, bf16* __restrict__ Z){
  int dir = blockIdx.z;
  const bf16* A = xln + (size_t)dir*BATCH*LLEN*128;
  const float* W = dir ? vw : hw;
  int m0 = blockIdx.x*64;
  int npair = blockIdx.y*128;     // covers n0 = npair, npair+64 (same XI/Z half)
  __shared__ __align__(16) bf16 sA[64][136];
  __shared__ __align__(16) bf16 sW[64][136];
  int tid = threadIdx.x;
  #pragma unroll
  for (int r=0;r<4;r++){
    int idx = tid + r*256;
    int row = idx >> 4, c8 = (idx & 15)*8;
    *reinterpret_cast<float4*>(&sA[row][c8]) =
        *reinterpret_cast<const float4*>(&A[(size_t)(m0+row)*128 + c8]);
  }
  int wv2 = tid >> 6, lane = tid & 63;
  int qd = lane >> 4, mr = lane & 15;
  bf16* dst = (npair < 256) ? XI : Z;
  int nbase0 = npair & 255;
  size_t dslab = (size_t)dir*BATCH*LLEN*256;
  #pragma unroll
  for (int nt=0; nt<2; nt++){
    int n0 = npair + nt*64;
    __syncthreads();
    #pragma unroll
    for (int r=0;r<8;r++){
      int idx = tid + r*256;
      int row = idx >> 5, c4 = (idx & 31)*4;
      float4 w4 = *reinterpret_cast<const float4*>(&W[(size_t)(n0+row)*128 + c4]);
      bf16 t4[4] = {f2b(w4.x), f2b(w4.y), f2b(w4.z), f2b(w4.w)};
      *reinterpret_cast<double*>(&sW[row][c4]) = *reinterpret_cast<double*>(t4);
    }
    __syncthreads();
    frag_cd acc[4] = {};
    #pragma unroll
    for (int k0=0;k0<128;k0+=32){
      frag_ab af = *reinterpret_cast<frag_ab*>(&sA[wv2*16+mr][k0+qd*8]);
      #pragma unroll
      for (int t=0;t<4;t++){
        frag_ab bfr = *reinterpret_cast<frag_ab*>(&sW[t*16+mr][k0+qd*8]);
        acc[t] = __builtin_amdgcn_mfma_f32_16x16x32_bf16(af, bfr, acc[t], 0, 0, 0);
      }
    }
    int nb = nbase0 + nt*64;
    #pragma unroll
    for (int t=0;t<4;t++)
      #pragma unroll
      for (int r=0;r<4;r++){
        int row = m0 + wv2*16 + qd*4 + r;
        int col = nb + t*16 + mr;
        dst[dslab + (size_t)row*256 + col] = f2b(acc[t][r]);
      }
  }
}

// ---------------- causal depthwise conv1d(k=4) + silu; writes XS2 (scan layout) only ----------------
__global__ void k_conv(const bf16* __restrict__ XI, const float* hw, const float* hb,
                       const float* vw, const float* vb, bf16* __restrict__ XS2){
  int dir = blockIdx.z;
  int b = blockIdx.y;
  int bd = dir*BATCH + b;
  int l0 = blockIdx.x * 32;
  const bf16* XId = XI + (size_t)bd*LLEN*256;
  const float* cw = dir ? vw : hw;
  const float* cb = dir ? vb : hb;
  __shared__ float sxi[35][256];
  int tid = threadIdx.x;
  for (int r = 0; r < 35; r++){
    int l = l0 - 3 + r;
    sxi[r][tid] = (l >= 0) ? b2f(XId[(size_t)l*256 + tid]) : 0.f;
  }
  __syncthreads();
  float w0=cw[tid*4], w1=cw[tid*4+1], w2=cw[tid*4+2], w3=cw[tid*4+3];
  float bias = cb[tid];
  size_t x2base = ((size_t)bd*16 + (tid>>4))*LLEN;
  int c16 = tid & 15;
  for (int ll=0; ll<32; ll++){
    float acc = bias + w0*sxi[ll][tid] + w1*sxi[ll+1][tid] + w2*sxi[ll+2][tid] + w3*sxi[ll+3][tid];
    float s = acc / (1.f + __expf(-acc));
    XS2[(x2base + l0 + ll)*16 + c16] = f2b(s);
  }
}

// ---------------- xproj fused (MFMA): DBL -> dt->DT2, B/C extract, + fused scan pass 1 ----------------
__global__ void k_dbl(const bf16* __restrict__ XS2, const float* __restrict__ hx,
                      const float* __restrict__ vx,
                      const float* hdw, const float* vdw, const float* hdb, const float* vdb,
                      const float* hA, const float* vA,
                      bf16* __restrict__ DT2, float* __restrict__ Bf, float* __restrict__ Cf,
                      float* __restrict__ Pbuf, float* __restrict__ Hbuf){
  int m0 = blockIdx.x*64;                      // 196 tiles; never crosses bd boundary
  int bd = m0 / LLEN;
  int l0m = m0 % LLEN;
  int ck = l0m / LC;
  int dirq = bd >> 1;
  const float* W = dirq ? vx : hx;
  __shared__ __align__(16) bf16 sA[64][264];   // 33.8 KB (xs, stays live for scan)
  __shared__ __align__(16) bf16 sW[48][264];   // 25.3 KB (rows 40..47 zero)
  __shared__ float sdbl[64][49];               // 12.5 KB (B at [row][8+n], stays live)
  int tid = threadIdx.x;
  #pragma unroll
  for (int r=0;r<8;r++){
    int idx = tid + r*256;
    int row = idx >> 5, c8 = (idx & 31)*8;
    size_t src = (((size_t)bd*16 + (c8>>4))*LLEN + l0m + row)*16 + (c8&15);
    *reinterpret_cast<float4*>(&sA[row][c8]) =
        *reinterpret_cast<const float4*>(&XS2[src]);
  }
  #pragma unroll
  for (int r=0;r<12;r++){
    int idx = tid + r*256;                     // 3072 = 48*64 chunks of 4
    int row = idx >> 6, c4 = (idx & 63)*4;
    bf16 t4[4] = {f2b(0.f), f2b(0.f), f2b(0.f), f2b(0.f)};
    if (row < 40){
      float4 w4 = *reinterpret_cast<const float4*>(&W[(size_t)row*256 + c4]);
      t4[0]=f2b(w4.x); t4[1]=f2b(w4.y); t4[2]=f2b(w4.z); t4[3]=f2b(w4.w);
    }
    *reinterpret_cast<double*>(&sW[row][c4]) = *reinterpret_cast<double*>(t4);
  }
  __syncthreads();
  int wv2 = tid >> 6, lane = tid & 63;
  int qd = lane >> 4, mr = lane & 15;
  frag_cd acc[3] = {};
  #pragma unroll
  for (int k0=0;k0<256;k0+=32){
    frag_ab af = *reinterpret_cast<frag_ab*>(&sA[wv2*16+mr][k0+qd*8]);
    #pragma unroll
    for (int t=0;t<3;t++){
      frag_ab bfr = *reinterpret_cast<frag_ab*>(&sW[t*16+mr][k0+qd*8]);
      acc[t] = __builtin_amdgcn_mfma_f32_16x16x32_bf16(af, bfr, acc[t], 0, 0, 0);
    }
  }
  #pragma unroll
  for (int t=0;t<3;t++)
    #pragma unroll
    for (int r=0;r<4;r++){
      int col = t*16 + mr;
      if (col < 40) sdbl[wv2*16 + qd*4 + r][col] = acc[t][r];
    }
  __syncthreads();
  const float* dtw = dirq ? vdw : hdw;
  const float* dtb = dirq ? vdb : hdb;
  const float* Alog = dirq ? vA : hA;
  float w8[8];
  #pragma unroll
  for (int r=0;r<8;r++) w8[r] = dtw[tid*8+r];
  float biasv = dtb[tid];
  float Aq[16];
  #pragma unroll
  for (int n=0;n<16;n++) Aq[n] = -__expf(Alog[tid*16+n]);
  float hst[16] = {};
  float Pst[16];
  #pragma unroll
  for (int n=0;n<16;n++) Pst[n] = 1.f;
  size_t d2base = ((size_t)bd*16 + (tid>>4))*LLEN + l0m;
  int c16 = tid & 15;
  for (int row=0; row<64; row++){
    float a = biasv;
    #pragma unroll
    for (int r=0;r<8;r++) a += sdbl[row][r]*w8[r];
    float sv = (a > 20.f) ? a : __logf(1.f + __expf(a));
    bf16 svb16 = f2b(sv);
    DT2[(d2base + row)*16 + c16] = svb16;
    float svb = b2f(svb16);                    // match scan3's bf16-rounded dt
    float u = b2f(sA[row][tid]);
    float au = svb*u;
    #pragma unroll
    for (int n=0;n<16;n++){
      float dA = __expf(svb * Aq[n]);
      hst[n] = dA*hst[n] + au*sdbl[row][8+n];
      Pst[n] *= dA;
    }
  }
  size_t pbase = (((size_t)bd*16 + (tid>>4))*NCHUNK + ck)*256 + (size_t)(tid&15)*16;
  #pragma unroll
  for (int n=0;n<16;n++){ Pbuf[pbase+n] = Pst[n]; Hbuf[pbase+n] = hst[n]; }
  #pragma unroll
  for (int r=0;r<8;r++){
    int idx = tid + r*256;                     // 2048 = 64 rows * 32 vals
    int row = idx >> 5, o = idx & 31;
    float v = sdbl[row][8+o];
    size_t rr = (size_t)(m0+row)*16;
    if (o < 16) Bf[rr + o] = v;
    else        Cf[rr + (o-16)] = v;
  }
}

// ---------------- pass 3: in-block prefix (replaces scan2) + local scan, LDS reduce, emit y ----------------
__global__ void k_scan3(const bf16* __restrict__ DT2, const bf16* __restrict__ XS2,
                        const float* __restrict__ Bc, const float* __restrict__ Cc,
                        const float* hA, const float* vA,
                        const float* __restrict__ Pbuf, const float* __restrict__ Hbuf,
                        bf16* __restrict__ ys){
  int bd = blockIdx.z;
  int g  = blockIdx.y;
  int ck = blockIdx.x;
  int l0 = ck*LC;
  const float* Bd = Bc + (size_t)bd*LLEN*16;
  const float* Cd = Cc + (size_t)bd*LLEN*16;
  bf16* yd = ys + (size_t)bd*LLEN*256;
  const float* Alog = (bd >> 1) ? vA : hA;
  int tid = threadIdx.x;
  int dl = tid >> 4, n = tid & 15;
  float A = -__expf(Alog[(g*16+dl)*16+n]);
  __shared__ float sdt[LC][16], sxs[LC][16], sB[LC][16], sC[LC][16];
  __shared__ __align__(16) float sp2[16][276];   // 17.7 KB; subchunk partial products
  // h_init: per-lane prefix combine over chunks 0..ck-1 (scan2 math, local)
  size_t qbase = ((size_t)bd*16 + g)*NCHUNK*256 + tid;
  float h = 0.f;
  for (int k=0;k<ck;k++){
    size_t idx = qbase + (size_t)k*256;
    h = Pbuf[idx]*h + Hbuf[idx];
  }
  size_t base2 = (((size_t)bd*16 + g)*LLEN + l0)*16;
  #pragma unroll
  for (int r=0;r<4;r++){
    int idx = tid + r*256;
    sdt[idx>>4][idx&15] = b2f(DT2[base2 + idx]);
    sxs[idx>>4][idx&15] = b2f(XS2[base2 + idx]);
    (&sB[0][0])[idx] = Bd[(size_t)l0*16 + idx];
    (&sC[0][0])[idx] = Cd[(size_t)l0*16 + idx];
  }
  __syncthreads();
  int i_local = tid >> 4;        // reduce-phase: step within subchunk
  int c16 = tid & 15;            // reduce-phase: channel-in-group
  for (int i0=0; i0<LC; i0+=16){
    #pragma unroll
    for (int ii=0;ii<16;ii++){
      int i = i0 + ii;
      float a = sdt[i][dl];
      float u = sxs[i][dl];
      float dA = __expf(a * A);
      h = dA*h + (a*u)*sB[i][n];
      sp2[ii][tid] = h * sC[i][n];
    }
    __syncthreads();
    const float* row = &sp2[i_local][c16*16];
    float s = 0.f;
    #pragma unroll
    for (int k=0;k<4;k++){
      float4 v = *reinterpret_cast<const float4*>(row + k*4);
      s += v.x + v.y + v.z + v.w;
    }
    yd[(size_t)(l0+i0+i_local)*256 + g*16 + c16] = f2b(s);
    __syncthreads();
  }
}

// ---------------- out_proj GEMM (MFMA bf16): 32-row tiles, both n-halves, YF staged once ----------------
__global__ void k_outgemm(const bf16* __restrict__ ys, const bf16* __restrict__ XS2,
                          const bf16* __restrict__ Z, const float* __restrict__ hD,
                          const float* __restrict__ vD, const float* __restrict__ how,
                          const float* __restrict__ vow, bf16* __restrict__ OD){
  int dir = blockIdx.y;
  size_t slab = (size_t)dir*BATCH*LLEN*256;
  const float* W = dir ? vow : how;
  const float* Dw = dir ? vD : hD;
  bf16* od = OD + (size_t)dir*BATCH*LLEN*128;
  int m0 = blockIdx.x*32;        // 196 m-tiles per dir; 3136 % 32 == 0
  int bd = dir*2 + m0/LLEN;
  int lbase = m0 % LLEN;
  __shared__ __align__(16) bf16 sA[32][264];   // 16.9 KB
  __shared__ __align__(16) bf16 sW[64][264];   // 33.8 KB
  int tid = threadIdx.x;
  #pragma unroll
  for (int r=0;r<4;r++){
    int idx = tid + r*256;                     // 1024 chunks of 8
    int row = idx >> 5, c8 = (idx & 31)*8;
    size_t e = slab + (size_t)(m0+row)*256 + c8;
    size_t e2 = (((size_t)bd*16 + (c8>>4))*LLEN + lbase + row)*16 + (c8&15);
    bf16 yb[8], xb[8], zb[8], ob[8];
    *reinterpret_cast<float4*>(yb) = *reinterpret_cast<const float4*>(&ys[e]);
    *reinterpret_cast<float4*>(xb) = *reinterpret_cast<const float4*>(&XS2[e2]);
    *reinterpret_cast<float4*>(zb) = *reinterpret_cast<const float4*>(&Z[e]);
    #pragma unroll
    for (int j=0;j<8;j++){
      float Dv = Dw[c8 + j];
      float yv = b2f(yb[j]) + b2f(xb[j])*Dv;
      float zv = b2f(zb[j]);
      ob[j] = f2b(yv * (zv/(1.f+__expf(-zv))));
    }
    *reinterpret_cast<float4*>(&sA[row][c8]) = *reinterpret_cast<float4*>(ob);
  }
  int wv2 = tid >> 6, lane = tid & 63;
  int qd = lane >> 4, mr = lane & 15;
  int msub = wv2 & 1, tpair = (wv2 >> 1)*2;
  #pragma unroll
  for (int nh=0; nh<2; nh++){
    int n0 = nh*64;
    __syncthreads();
    #pragma unroll
    for (int r=0;r<16;r++){
      int idx = tid + r*256;                   // 4096 chunks of 4
      int row = idx >> 6, c4 = (idx & 63)*4;
      float4 w4 = *reinterpret_cast<const float4*>(&W[(size_t)(n0+row)*256 + c4]);
      bf16 t4[4] = {f2b(w4.x), f2b(w4.y), f2b(w4.z), f2b(w4.w)};
      *reinterpret_cast<double*>(&sW[row][c4]) = *reinterpret_cast<double*>(t4);
    }
    __syncthreads();
    frag_cd acc[2] = {};
    #pragma unroll
    for (int k0=0;k0<256;k0+=32){
      frag_ab af = *reinterpret_cast<frag_ab*>(&sA[msub*16+mr][k0+qd*8]);
      #pragma unroll
      for (int i=0;i<2;i++){
        frag_ab bfr = *reinterpret_cast<frag_ab*>(&sW[(tpair+i)*16+mr][k0+qd*8]);
        acc[i] = __builtin_amdgcn_mfma_f32_16x16x32_bf16(af, bfr, acc[i], 0, 0, 0);
      }
    }
    #pragma unroll
    for (int i=0;i<2;i++)
      #pragma unroll
      for (int r=0;r<4;r++){
        int row = m0 + msub*16 + qd*4 + r;
        int col = n0 + (tpair+i)*16 + mr;
        od[(size_t)row*128 + col] = f2b(acc[i][r]);
      }
  }
}

// ---------------- pw conv (MFMA) + combine OD + OD^T + YMEAN partials, single FUSED write ----------------
__global__ void k_pwcomb(const bf16* __restrict__ tmp, const float* __restrict__ pww,
                         const float* __restrict__ pwb, const bf16* __restrict__ OD,
                         float* __restrict__ fused, float* __restrict__ YMEAN){
  int p0 = blockIdx.x * 64;       // 49 p-tiles
  int m0 = blockIdx.y * 64;       // 2 out-channel halves
  int b  = blockIdx.z;
  const bf16* T = tmp + (size_t)b*128*LLEN;
  const bf16* od0 = OD + (size_t)b*LLEN*128;
  const bf16* od1 = OD + (size_t)(BATCH + b)*LLEN*128;
  __shared__ __align__(16) bf16 sA[64][136];    // pww rows m0.., k=c (bf16)
  __shared__ __align__(16) bf16 sBt[64][132];   // [p][c] transposed tmp tile
  __shared__ float sOD[64][65];                 // [p][m] od0 + od1^T
  int tid = threadIdx.x;
  #pragma unroll
  for (int r=0;r<8;r++){
    int idx = tid + r*256;
    int row = idx >> 5, c4 = (idx & 31)*4;
    float4 w4 = *reinterpret_cast<const float4*>(&pww[(size_t)(m0+row)*128 + c4]);
    bf16 t4[4] = {f2b(w4.x), f2b(w4.y), f2b(w4.z), f2b(w4.w)};
    *reinterpret_cast<double*>(&sA[row][c4]) = *reinterpret_cast<double*>(t4);
  }
  #pragma unroll
  for (int r=0;r<8;r++){
    int idx = tid + r*256;
    int c = idx >> 4, p4 = (idx & 15)*4;
    union { double d; bf16 v[4]; } u;
    u.d = *reinterpret_cast<const double*>(&T[(size_t)c*LLEN + p0 + p4]);
    #pragma unroll
    for (int j=0;j<4;j++) sBt[p4+j][c] = u.v[j];
  }
  #pragma unroll
  for (int r=0;r<8;r++){
    int idx = tid + r*256;       // 2048 = 64 p-rows * 32 m-pairs
    int prow = idx >> 5, mp = (idx & 31)*2;
    int p = p0 + prow;
    int pi = p/56, pj = p%56;
    int pt = pj*56 + pi;
    bf16 a0[2], a1[2];
    *reinterpret_cast<float*>(a0) = *reinterpret_cast<const float*>(&od0[(size_t)p*128 + m0 + mp]);
    *reinterpret_cast<float*>(a1) = *reinterpret_cast<const float*>(&od1[(size_t)pt*128 + m0 + mp]);
    sOD[prow][mp]   = b2f(a0[0]) + b2f(a1[0]);
    sOD[prow][mp+1] = b2f(a0[1]) + b2f(a1[1]);
  }
  __syncthreads();
  int wv2 = tid >> 6, lane = tid & 63;
  int qd = lane >> 4, mr = lane & 15;
  frag_cd acc[4] = {};
  #pragma unroll
  for (int k0=0;k0<128;k0+=32){
    frag_ab af = *reinterpret_cast<frag_ab*>(&sA[wv2*16+mr][k0+qd*8]);
    #pragma unroll
    for (int t=0;t<4;t++){
      frag_ab bfr = ld_frag_2xb64(&sBt[t*16+mr][k0+qd*8]);
      acc[t] = __builtin_amdgcn_mfma_f32_16x16x32_bf16(af, bfr, acc[t], 0, 0, 0);
    }
  }
  #pragma unroll
  for (int r=0;r<4;r++){
    int m = m0 + wv2*16 + qd*4 + r;
    float bias = pwb[m];
    float s = 0.f;
    #pragma unroll
    for (int t=0;t<4;t++){
      int p = p0 + t*16 + mr;
      float val = acc[t][r] + bias + sOD[t*16+mr][m - m0];
      fused[((size_t)b*128 + m)*LLEN + p] = val;
      s += val;
    }
    s += __shfl_xor(s, 1, 16);
    s += __shfl_xor(s, 2, 16);
    s += __shfl_xor(s, 4, 16);
    s += __shfl_xor(s, 8, 16);
    if (mr == 0) atomicAdd(&YMEAN[b*128 + m], s);
  }
}

// ---------------- final: compute gate per (b,c) in-block, out = fused*gate + x ----------------
__global__ void k_final_gate(const float* __restrict__ fused, const float* __restrict__ YMEAN,
                             const float* __restrict__ fc1, const float* __restrict__ fc2,
                             const float* __restrict__ x, float* __restrict__ out){
  int bc = blockIdx.y;           // 0..255
  int b = bc >> 7, c = bc & 127;
  __shared__ float ym[128], s1[32];
  __shared__ float gsh;
  int tid = threadIdx.x;
  if (tid < 128) ym[tid] = YMEAN[b*128 + tid] * (1.f/(float)LLEN);
  __syncthreads();
  if (tid < 32){
    float a = 0.f;
    for (int cc=0;cc<128;cc++) a += ym[cc]*fc1[tid*128+cc];
    s1[tid] = fmaxf(a, 0.f);
  }
  __syncthreads();
  if (tid == 0){
    float a = 0.f;
    #pragma unroll
    for (int j=0;j<32;j++) a += s1[j]*fc2[c*32+j];
    gsh = 1.f/(1.f+__expf(-a));
  }
  __syncthreads();
  float g = gsh;
  int p = blockIdx.x*256 + tid;
  if (p < LLEN){
    size_t i = (size_t)bc*LLEN + p;
    out[i] = fused[i]*g + x[i];
  }
}

extern "C" void kernel_launch(void* const* d_in, const int* in_sizes, int n_in,
                              void* d_out, int out_size, void* d_ws, size_t ws_size,
                              hipStream_t stream) {
  const float* x      = (const float*)d_in[0];
  const float* nhw    = (const float*)d_in[1];
  const float* nhb    = (const float*)d_in[2];
  const float* nvw    = (const float*)d_in[3];
  const float* nvb    = (const float*)d_in[4];
  const float* dww    = (const float*)d_in[5];
  const float* dwb    = (const float*)d_in[6];
  const float* pww    = (const float*)d_in[7];
  const float* pwb    = (const float*)d_in[8];
  const float* h_inw  = (const float*)d_in[9];
  const float* h_cw   = (const float*)d_in[10];
  const float* h_cb   = (const float*)d_in[11];
  const float* h_xw   = (const float*)d_in[12];
  const float* h_dtw  = (const float*)d_in[13];
  const float* h_dtb  = (const float*)d_in[14];
  const float* h_Al   = (const float*)d_in[15];
  const float* h_D    = (const float*)d_in[16];
  const float* h_ow   = (const float*)d_in[17];
  const float* v_inw  = (const float*)d_in[18];
  const float* v_cw   = (const float*)d_in[19];
  const float* v_cb   = (const float*)d_in[20];
  const float* v_xw   = (const float*)d_in[21];
  const float* v_dtw  = (const float*)d_in[22];
  const float* v_dtb  = (const float*)d_in[23];
  const float* v_Al   = (const float*)d_in[24];
  const float* v_D    = (const float*)d_in[25];
  const float* v_ow   = (const float*)d_in[26];
  const float* fc1    = (const float*)d_in[27];
  const float* fc2    = (const float*)d_in[28];

  float* FUSED = (float*)d_out;   // FUSED lives in d_out; k_final_gate is in-place elementwise
  float* out   = (float*)d_out;

  // Workspace layout (bytes), high-water ~32.1 MB. Stream-ordered-safe aliases:
  //  DT2 at base+0 (XLN under it dead after k_inproj); OD overlays DT2 (dead after k_scan3)
  //  YS overlays XI (dead after k_conv); Pbuf overlays YS head (dead before k_scan3 writes YS?
  //   -- NOTE: Pbuf/Hbuf are READ by k_scan3 while it writes YS. Pbuf moved OFF the YS alias.)
  char* base = (char*)d_ws;
  bf16*  XLN   = (bf16*)(base + 1605632);     // 3,211,264 B
  bf16*  DT2   = (bf16*)(base + 0);           // 6,422,528 B  [overlays XLN region; scan layout]
  bf16*  OD    = (bf16*)(base + 0);           // 3,211,264 B  [alias DT2; live after k_scan3]
  bf16*  XI    = (bf16*)(base + 6422528);     // 6,422,528 B
  bf16*  YS    = (bf16*)(base + 6422528);     // 6,422,528 B  [alias XI]
  bf16*  Z     = (bf16*)(base + 12845056);    // 6,422,528 B
  bf16*  XS2   = (bf16*)(base + 19267584);    // 6,422,528 B  [scan layout]
  float* Bf    = (float*)(base + 25690112);   //   802,816 B
  float* Cf    = (float*)(base + 26492928);   //   802,816 B
  float* Hbuf  = (float*)(base + 27295744);   // 3,211,264 B
  float* YMEAN = (float*)(base + 30507008);   //     1,024 B
  bf16*  TMP   = (bf16*)(base + 30508032);    // 1,605,632 B  (ends 32,113,664)
  float* Pbuf  = (float*)(base + 32113664);   // 3,211,264 B  (ends 35,324,928)

  k_front<<<dim3(1024 + 56*BATCH), dim3(256), 0, stream>>>(x, dww, dwb, TMP,
                                                           nhw, nhb, nvw, nvb, XLN, YMEAN);
  k_inproj<<<dim3(98,4,2), dim3(256), 0, stream>>>(XLN, h_inw, v_inw, XI, Z);
  k_conv<<<dim3(98,BATCH,2), dim3(256), 0, stream>>>(XI, h_cw, h_cb, v_cw, v_cb, XS2);
  k_dbl<<<dim3(196), dim3(256), 0, stream>>>(XS2, h_xw, v_xw, h_dtw, v_dtw, h_dtb, v_dtb,
                                             h_Al, v_Al, DT2, Bf, Cf, Pbuf, Hbuf);
  k_scan3<<<dim3(NCHUNK,16,4), dim3(256), 0, stream>>>(DT2, XS2, Bf, Cf, h_Al, v_Al,
                                                       Pbuf, Hbuf, YS);
  k_outgemm<<<dim3(196,2), dim3(256), 0, stream>>>(YS, XS2, Z, h_D, v_D, h_ow, v_ow, OD);
  k_pwcomb<<<dim3(49,2,BATCH), dim3(256), 0, stream>>>(TMP, pww, pwb, OD, FUSED, YMEAN);
  k_final_gate<<<dim3(13,256), dim3(256), 0, stream>>>(FUSED, YMEAN, fc1, fc2, x, out);
}

// Round 17
// 247.616 us; speedup vs baseline: 1.0614x; 1.0614x over previous
//
#include <hip/hip_runtime.h>
#include <hip/hip_bf16.h>

typedef __hip_bfloat16 bf16;
__device__ __forceinline__ float b2f(bf16 v){ return __bfloat162float(v); }
__device__ __forceinline__ bf16 f2b(float v){ return __float2bfloat16(v); }

typedef __attribute__((ext_vector_type(8))) short frag_ab;   // 8 bf16 (4 VGPRs)
typedef __attribute__((ext_vector_type(4))) float frag_cd;   // 4 fp32 acc
typedef __attribute__((ext_vector_type(4))) short short4v;   // 8B

__device__ __forceinline__ frag_ab ld_frag_2xb64(const bf16* p){
  union { frag_ab f; short4v h[2]; } u;
  u.h[0] = *reinterpret_cast<const short4v*>(p);
  u.h[1] = *reinterpret_cast<const short4v*>(p+4);
  return u.f;
}

#define LLEN 3136
#define BATCH 2
#define NCHUNK 49
#define LC 64

// ---------------- fused: dwconv3x3+gelu (blocks 0..1023) | LayerNorm (blocks 1024..1135) ----------------
__global__ void k_front(const float* __restrict__ x, const float* __restrict__ dww,
                        const float* __restrict__ dwb, bf16* __restrict__ tmp,
                        const float* nhw_, const float* nhb_, const float* nvw_,
                        const float* nvb_, bf16* __restrict__ xln,
                        float* __restrict__ YMEAN){
  int blk = blockIdx.x;
  int tid = threadIdx.x;
  if (blk < 1024){
    int bc = blk & 255;            // b*128 + c
    int seg = blk >> 8;
    int c = bc & 127;
    if (bc == 0 && seg == 0 && tid < 256) YMEAN[tid] = 0.f;
    const float* xp = x + (size_t)bc*LLEN;
    float w[9];
    #pragma unroll
    for (int i=0;i<9;i++) w[i] = dww[c*9+i];
    float bias = dwb[c];
    int pstart = seg * 784;
    for (int p = pstart + tid; p < pstart + 784; p += 256){
      int i = p/56, j = p%56;
      float acc = bias;
      #pragma unroll
      for (int a=0;a<3;a++){
        int ii = i + a - 1;
        if (ii < 0 || ii >= 56) continue;
        #pragma unroll
        for (int bb=0;bb<3;bb++){
          int jj = j + bb - 1;
          if (jj < 0 || jj >= 56) continue;
          acc += w[a*3+bb] * xp[ii*56+jj];
        }
      }
      float g = 0.5f*acc*(1.0f + erff(acc*0.70710678118654752f));
      tmp[(size_t)bc*LLEN + p] = f2b(g);
    }
  } else {
    int idx2 = blk - 1024;         // 0..111
    int h = idx2 % 56, b = idx2 / 56;
    __shared__ float sx[128][57];
    __shared__ float smean[56], srstd[56];
    __shared__ float wh[128], bh[128], wv_[128], bv_[128];
    if (tid < 128){ wh[tid]=nhw_[tid]; bh[tid]=nhb_[tid];
                    wv_[tid]=nvw_[tid]; bv_[tid]=nvb_[tid]; }
    for (int idx = tid; idx < 128*56; idx += 256){
      int c = idx / 56, w = idx % 56;
      sx[c][w] = x[((size_t)(b*128+c))*LLEN + h*56 + w];
    }
    __syncthreads();
    if (tid < 56){
      float s=0.f, s2=0.f;
      for (int c=0;c<128;c++){ float v = sx[c][tid]; s+=v; s2+=v*v; }
      float m = s*(1.f/128.f);
      float var = s2*(1.f/128.f) - m*m;
      smean[tid]=m; srstd[tid]=rsqrtf(var+1e-5f);
    }
    __syncthreads();
    bf16* outh = xln;
    bf16* outv = xln + (size_t)BATCH*LLEN*128;
    for (int idx = tid; idx < 56*128; idx += 256){
      int w = idx >> 7, c = idx & 127;
      float v = (sx[c][w]-smean[w])*srstd[w];
      outh[((size_t)b*LLEN + h*56 + w)*128 + c] = f2b(v*wh[c]+bh[c]);
      outv[((size_t)b*LLEN + w*56 + h)*128 + c] = f2b(v*wv_[c]+bv_[c]);
    }
  }
}

// ---------------- in_proj GEMM (MFMA bf16): 64-row tile, 2 n-tiles per block (A staged once) ----------------
__global__ void k_inproj(const bf16* __restrict__ xln, const float* __restrict__ hw,
                         const float* __restrict__ vw, bf16* __restrict__ XI, bf16* __restrict__ Z){
  int dir = blockIdx.z;
  const bf16* A = xln + (size_t)dir*BATCH*LLEN*128;
  const float* W = dir ? vw : hw;
  int m0 = blockIdx.x*64;
  int npair = blockIdx.y*128;     // covers n0 = npair, npair+64 (same XI/Z half)
  __shared__ __align__(16) bf16 sA[64][136];
  __shared__ __align__(16) bf16 sW[64][136];
  int tid = threadIdx.x;
  #pragma unroll
  for (int r=0;r<4;r++){
    int idx = tid + r*256;
    int row = idx >> 4, c8 = (idx & 15)*8;
    *reinterpret_cast<float4*>(&sA[row][c8]) =
        *reinterpret_cast<const float4*>(&A[(size_t)(m0+row)*128 + c8]);
  }
  int wv2 = tid >> 6, lane = tid & 63;
  int qd = lane >> 4, mr = lane & 15;
  bf16* dst = (npair < 256) ? XI : Z;
  int nbase0 = npair & 255;
  size_t dslab = (size_t)dir*BATCH*LLEN*256;
  #pragma unroll
  for (int nt=0; nt<2; nt++){
    int n0 = npair + nt*64;
    __syncthreads();
    #pragma unroll
    for (int r=0;r<8;r++){
      int idx = tid + r*256;
      int row = idx >> 5, c4 = (idx & 31)*4;
      float4 w4 = *reinterpret_cast<const float4*>(&W[(size_t)(n0+row)*128 + c4]);
      bf16 t4[4] = {f2b(w4.x), f2b(w4.y), f2b(w4.z), f2b(w4.w)};
      *reinterpret_cast<double*>(&sW[row][c4]) = *reinterpret_cast<double*>(t4);
    }
    __syncthreads();
    frag_cd acc[4] = {};
    #pragma unroll
    for (int k0=0;k0<128;k0+=32){
      frag_ab af = *reinterpret_cast<frag_ab*>(&sA[wv2*16+mr][k0+qd*8]);
      #pragma unroll
      for (int t=0;t<4;t++){
        frag_ab bfr = *reinterpret_cast<frag_ab*>(&sW[t*16+mr][k0+qd*8]);
        acc[t] = __builtin_amdgcn_mfma_f32_16x16x32_bf16(af, bfr, acc[t], 0, 0, 0);
      }
    }
    int nb = nbase0 + nt*64;
    #pragma unroll
    for (int t=0;t<4;t++)
      #pragma unroll
      for (int r=0;r<4;r++){
        int row = m0 + wv2*16 + qd*4 + r;
        int col = nb + t*16 + mr;
        dst[dslab + (size_t)row*256 + col] = f2b(acc[t][r]);
      }
  }
}

// ---------------- causal depthwise conv1d(k=4) + silu; writes XS2 (scan layout) only ----------------
__global__ void k_conv(const bf16* __restrict__ XI, const float* hw, const float* hb,
                       const float* vw, const float* vb, bf16* __restrict__ XS2){
  int dir = blockIdx.z;
  int b = blockIdx.y;
  int bd = dir*BATCH + b;
  int l0 = blockIdx.x * 32;
  const bf16* XId = XI + (size_t)bd*LLEN*256;
  const float* cw = dir ? vw : hw;
  const float* cb = dir ? vb : hb;
  __shared__ float sxi[35][256];
  int tid = threadIdx.x;
  for (int r = 0; r < 35; r++){
    int l = l0 - 3 + r;
    sxi[r][tid] = (l >= 0) ? b2f(XId[(size_t)l*256 + tid]) : 0.f;
  }
  __syncthreads();
  float w0=cw[tid*4], w1=cw[tid*4+1], w2=cw[tid*4+2], w3=cw[tid*4+3];
  float bias = cb[tid];
  size_t x2base = ((size_t)bd*16 + (tid>>4))*LLEN;
  int c16 = tid & 15;
  for (int ll=0; ll<32; ll++){
    float acc = bias + w0*sxi[ll][tid] + w1*sxi[ll+1][tid] + w2*sxi[ll+2][tid] + w3*sxi[ll+3][tid];
    float s = acc / (1.f + __expf(-acc));
    XS2[(x2base + l0 + ll)*16 + c16] = f2b(s);
  }
}

// ---------------- xproj fused (MFMA): DBL -> dt->DT2, B/C extract, + fused scan pass 1 ----------------
__global__ void k_dbl(const bf16* __restrict__ XS2, const float* __restrict__ hx,
                      const float* __restrict__ vx,
                      const float* hdw, const float* vdw, const float* hdb, const float* vdb,
                      const float* hA, const float* vA,
                      bf16* __restrict__ DT2, float* __restrict__ Bf, float* __restrict__ Cf,
                      float* __restrict__ Pbuf, float* __restrict__ Hbuf){
  int m0 = blockIdx.x*64;                      // 196 tiles; never crosses bd boundary
  int bd = m0 / LLEN;
  int l0m = m0 % LLEN;
  int ck = l0m / LC;
  int dirq = bd >> 1;
  const float* W = dirq ? vx : hx;
  __shared__ __align__(16) bf16 sA[64][264];   // 33.8 KB (xs, stays live for scan)
  __shared__ __align__(16) bf16 sW[48][264];   // 25.3 KB (rows 40..47 zero)
  __shared__ float sdbl[64][49];               // 12.5 KB (B at [row][8+n], stays live)
  int tid = threadIdx.x;
  #pragma unroll
  for (int r=0;r<8;r++){
    int idx = tid + r*256;
    int row = idx >> 5, c8 = (idx & 31)*8;
    size_t src = (((size_t)bd*16 + (c8>>4))*LLEN + l0m + row)*16 + (c8&15);
    *reinterpret_cast<float4*>(&sA[row][c8]) =
        *reinterpret_cast<const float4*>(&XS2[src]);
  }
  #pragma unroll
  for (int r=0;r<12;r++){
    int idx = tid + r*256;                     // 3072 = 48*64 chunks of 4
    int row = idx >> 6, c4 = (idx & 63)*4;
    bf16 t4[4] = {f2b(0.f), f2b(0.f), f2b(0.f), f2b(0.f)};
    if (row < 40){
      float4 w4 = *reinterpret_cast<const float4*>(&W[(size_t)row*256 + c4]);
      t4[0]=f2b(w4.x); t4[1]=f2b(w4.y); t4[2]=f2b(w4.z); t4[3]=f2b(w4.w);
    }
    *reinterpret_cast<double*>(&sW[row][c4]) = *reinterpret_cast<double*>(t4);
  }
  __syncthreads();
  int wv2 = tid >> 6, lane = tid & 63;
  int qd = lane >> 4, mr = lane & 15;
  frag_cd acc[3] = {};
  #pragma unroll
  for (int k0=0;k0<256;k0+=32){
    frag_ab af = *reinterpret_cast<frag_ab*>(&sA[wv2*16+mr][k0+qd*8]);
    #pragma unroll
    for (int t=0;t<3;t++){
      frag_ab bfr = *reinterpret_cast<frag_ab*>(&sW[t*16+mr][k0+qd*8]);
      acc[t] = __builtin_amdgcn_mfma_f32_16x16x32_bf16(af, bfr, acc[t], 0, 0, 0);
    }
  }
  #pragma unroll
  for (int t=0;t<3;t++)
    #pragma unroll
    for (int r=0;r<4;r++){
      int col = t*16 + mr;
      if (col < 40) sdbl[wv2*16 + qd*4 + r][col] = acc[t][r];
    }
  __syncthreads();
  const float* dtw = dirq ? vdw : hdw;
  const float* dtb = dirq ? vdb : hdb;
  const float* Alog = dirq ? vA : hA;
  float w8[8];
  #pragma unroll
  for (int r=0;r<8;r++) w8[r] = dtw[tid*8+r];
  float biasv = dtb[tid];
  float Aq[16];
  #pragma unroll
  for (int n=0;n<16;n++) Aq[n] = -__expf(Alog[tid*16+n]);
  float hst[16] = {};
  float Pst[16];
  #pragma unroll
  for (int n=0;n<16;n++) Pst[n] = 1.f;
  size_t d2base = ((size_t)bd*16 + (tid>>4))*LLEN + l0m;
  int c16 = tid & 15;
  for (int row=0; row<64; row++){
    float a = biasv;
    #pragma unroll
    for (int r=0;r<8;r++) a += sdbl[row][r]*w8[r];
    float sv = (a > 20.f) ? a : __logf(1.f + __expf(a));
    bf16 svb16 = f2b(sv);
    DT2[(d2base + row)*16 + c16] = svb16;
    float svb = b2f(svb16);                    // match scan3's bf16-rounded dt
    float u = b2f(sA[row][tid]);
    float au = svb*u;
    #pragma unroll
    for (int n=0;n<16;n++){
      float dA = __expf(svb * Aq[n]);
      hst[n] = dA*hst[n] + au*sdbl[row][8+n];
      Pst[n] *= dA;
    }
  }
  size_t pbase = (((size_t)bd*16 + (tid>>4))*NCHUNK + ck)*256 + (size_t)(tid&15)*16;
  #pragma unroll
  for (int n=0;n<16;n++){ Pbuf[pbase+n] = Pst[n]; Hbuf[pbase+n] = hst[n]; }
  #pragma unroll
  for (int r=0;r<8;r++){
    int idx = tid + r*256;                     // 2048 = 64 rows * 32 vals
    int row = idx >> 5, o = idx & 31;
    float v = sdbl[row][8+o];
    size_t rr = (size_t)(m0+row)*16;
    if (o < 16) Bf[rr + o] = v;
    else        Cf[rr + (o-16)] = v;
  }
}

// ---------------- pass 2: sequential combine over chunks (in-place h_end -> h_init) ----------------
__global__ void k_scan2(const float* __restrict__ Pbuf, float* __restrict__ Hbuf){
  int q = blockIdx.x;            // bd*16+g, 0..63
  int tid = threadIdx.x;
  float carry = 0.f;
  for (int k=0;k<NCHUNK;k++){
    size_t idx = ((size_t)q*NCHUNK + k)*256 + tid;
    float Pv = Pbuf[idx];
    float He = Hbuf[idx];
    Hbuf[idx] = carry;           // h_init for chunk k
    carry = Pv*carry + He;
  }
}

// ---------------- pass 3: local scan from h_init, swizzled LDS reduce (bank-conflict-free) ----------------
__global__ void k_scan3(const bf16* __restrict__ DT2, const bf16* __restrict__ XS2,
                        const float* __restrict__ Bc, const float* __restrict__ Cc,
                        const float* hA, const float* vA,
                        const float* __restrict__ Hbuf, bf16* __restrict__ ys){
  int bd = blockIdx.z;
  int g  = blockIdx.y;
  int ck = blockIdx.x;
  int l0 = ck*LC;
  const float* Bd = Bc + (size_t)bd*LLEN*16;
  const float* Cd = Cc + (size_t)bd*LLEN*16;
  bf16* yd = ys + (size_t)bd*LLEN*256;
  const float* Alog = (bd >> 1) ? vA : hA;
  int tid = threadIdx.x;
  int dl = tid >> 4, n = tid & 15;
  float A = -__expf(Alog[(g*16+dl)*16+n]);
  __shared__ float sdt[LC][16], sxs[LC][16], sB[LC][16], sC[LC][16];
  __shared__ float sp2[16][272];   // swizzled: element (dl,n) at dl*17+n -> <=2-way banks
  size_t base2 = (((size_t)bd*16 + g)*LLEN + l0)*16;
  #pragma unroll
  for (int r=0;r<4;r++){
    int idx = tid + r*256;
    sdt[idx>>4][idx&15] = b2f(DT2[base2 + idx]);
    sxs[idx>>4][idx&15] = b2f(XS2[base2 + idx]);
    (&sB[0][0])[idx] = Bd[(size_t)l0*16 + idx];
    (&sC[0][0])[idx] = Cd[(size_t)l0*16 + idx];
  }
  size_t sidx = (((size_t)bd*16 + g)*NCHUNK + ck)*256 + tid;
  float h = Hbuf[sidx];
  __syncthreads();
  int swz = dl*17 + n;           // write offset within sp2 row
  int i_local = tid >> 4;        // reduce-phase: step within subchunk
  int c16 = tid & 15;            // reduce-phase: channel-in-group
  int rbase = c16*17;            // read base within sp2 row
  for (int i0=0; i0<LC; i0+=16){
    #pragma unroll
    for (int ii=0;ii<16;ii++){
      int i = i0 + ii;
      float a = sdt[i][dl];
      float u = sxs[i][dl];
      float dA = __expf(a * A);
      h = dA*h + (a*u)*sB[i][n];
      sp2[ii][swz] = h * sC[i][n];
    }
    __syncthreads();
    const float* row = &sp2[i_local][rbase];
    float s = 0.f;
    #pragma unroll
    for (int k=0;k<16;k++) s += row[k];
    yd[(size_t)(l0+i0+i_local)*256 + g*16 + c16] = f2b(s);
    __syncthreads();
  }
}

// ---------------- out_proj GEMM (MFMA bf16): 32-row tiles, both n-halves, YF staged once ----------------
__global__ void k_outgemm(const bf16* __restrict__ ys, const bf16* __restrict__ XS2,
                          const bf16* __restrict__ Z, const float* __restrict__ hD,
                          const float* __restrict__ vD, const float* __restrict__ how,
                          const float* __restrict__ vow, bf16* __restrict__ OD){
  int dir = blockIdx.y;
  size_t slab = (size_t)dir*BATCH*LLEN*256;
  const float* W = dir ? vow : how;
  const float* Dw = dir ? vD : hD;
  bf16* od = OD + (size_t)dir*BATCH*LLEN*128;
  int m0 = blockIdx.x*32;        // 196 m-tiles per dir; 3136 % 32 == 0
  int bd = dir*2 + m0/LLEN;
  int lbase = m0 % LLEN;
  __shared__ __align__(16) bf16 sA[32][264];   // 16.9 KB
  __shared__ __align__(16) bf16 sW[64][264];   // 33.8 KB
  int tid = threadIdx.x;
  #pragma unroll
  for (int r=0;r<4;r++){
    int idx = tid + r*256;                     // 1024 chunks of 8
    int row = idx >> 5, c8 = (idx & 31)*8;
    size_t e = slab + (size_t)(m0+row)*256 + c8;
    size_t e2 = (((size_t)bd*16 + (c8>>4))*LLEN + lbase + row)*16 + (c8&15);
    bf16 yb[8], xb[8], zb[8], ob[8];
    *reinterpret_cast<float4*>(yb) = *reinterpret_cast<const float4*>(&ys[e]);
    *reinterpret_cast<float4*>(xb) = *reinterpret_cast<const float4*>(&XS2[e2]);
    *reinterpret_cast<float4*>(zb) = *reinterpret_cast<const float4*>(&Z[e]);
    #pragma unroll
    for (int j=0;j<8;j++){
      float Dv = Dw[c8 + j];
      float yv = b2f(yb[j]) + b2f(xb[j])*Dv;
      float zv = b2f(zb[j]);
      ob[j] = f2b(yv * (zv/(1.f+__expf(-zv))));
    }
    *reinterpret_cast<float4*>(&sA[row][c8]) = *reinterpret_cast<float4*>(ob);
  }
  int wv2 = tid >> 6, lane = tid & 63;
  int qd = lane >> 4, mr = lane & 15;
  int msub = wv2 & 1, tpair = (wv2 >> 1)*2;
  #pragma unroll
  for (int nh=0; nh<2; nh++){
    int n0 = nh*64;
    __syncthreads();
    #pragma unroll
    for (int r=0;r<16;r++){
      int idx = tid + r*256;                   // 4096 chunks of 4
      int row = idx >> 6, c4 = (idx & 63)*4;
      float4 w4 = *reinterpret_cast<const float4*>(&W[(size_t)(n0+row)*256 + c4]);
      bf16 t4[4] = {f2b(w4.x), f2b(w4.y), f2b(w4.z), f2b(w4.w)};
      *reinterpret_cast<double*>(&sW[row][c4]) = *reinterpret_cast<double*>(t4);
    }
    __syncthreads();
    frag_cd acc[2] = {};
    #pragma unroll
    for (int k0=0;k0<256;k0+=32){
      frag_ab af = *reinterpret_cast<frag_ab*>(&sA[msub*16+mr][k0+qd*8]);
      #pragma unroll
      for (int i=0;i<2;i++){
        frag_ab bfr = *reinterpret_cast<frag_ab*>(&sW[(tpair+i)*16+mr][k0+qd*8]);
        acc[i] = __builtin_amdgcn_mfma_f32_16x16x32_bf16(af, bfr, acc[i], 0, 0, 0);
      }
    }
    #pragma unroll
    for (int i=0;i<2;i++)
      #pragma unroll
      for (int r=0;r<4;r++){
        int row = m0 + msub*16 + qd*4 + r;
        int col = n0 + (tpair+i)*16 + mr;
        od[(size_t)row*128 + col] = f2b(acc[i][r]);
      }
  }
}

// ---------------- pw conv (MFMA) + combine OD + OD^T + YMEAN partials, single FUSED write ----------------
__global__ void k_pwcomb(const bf16* __restrict__ tmp, const float* __restrict__ pww,
                         const float* __restrict__ pwb, const bf16* __restrict__ OD,
                         float* __restrict__ fused, float* __restrict__ YMEAN){
  int p0 = blockIdx.x * 64;       // 49 p-tiles
  int m0 = blockIdx.y * 64;       // 2 out-channel halves
  int b  = blockIdx.z;
  const bf16* T = tmp + (size_t)b*128*LLEN;
  const bf16* od0 = OD + (size_t)b*LLEN*128;
  const bf16* od1 = OD + (size_t)(BATCH + b)*LLEN*128;
  __shared__ __align__(16) bf16 sA[64][136];    // pww rows m0.., k=c (bf16)
  __shared__ __align__(16) bf16 sBt[64][132];   // [p][c] transposed tmp tile
  __shared__ float sOD[64][65];                 // [p][m] od0 + od1^T
  int tid = threadIdx.x;
  #pragma unroll
  for (int r=0;r<8;r++){
    int idx = tid + r*256;
    int row = idx >> 5, c4 = (idx & 31)*4;
    float4 w4 = *reinterpret_cast<const float4*>(&pww[(size_t)(m0+row)*128 + c4]);
    bf16 t4[4] = {f2b(w4.x), f2b(w4.y), f2b(w4.z), f2b(w4.w)};
    *reinterpret_cast<double*>(&sA[row][c4]) = *reinterpret_cast<double*>(t4);
  }
  #pragma unroll
  for (int r=0;r<8;r++){
    int idx = tid + r*256;
    int c = idx >> 4, p4 = (idx & 15)*4;
    union { double d; bf16 v[4]; } u;
    u.d = *reinterpret_cast<const double*>(&T[(size_t)c*LLEN + p0 + p4]);
    #pragma unroll
    for (int j=0;j<4;j++) sBt[p4+j][c] = u.v[j];
  }
  #pragma unroll
  for (int r=0;r<8;r++){
    int idx = tid + r*256;       // 2048 = 64 p-rows * 32 m-pairs
    int prow = idx >> 5, mp = (idx & 31)*2;
    int p = p0 + prow;
    int pi = p/56, pj = p%56;
    int pt = pj*56 + pi;
    bf16 a0[2], a1[2];
    *reinterpret_cast<float*>(a0) = *reinterpret_cast<const float*>(&od0[(size_t)p*128 + m0 + mp]);
    *reinterpret_cast<float*>(a1) = *reinterpret_cast<const float*>(&od1[(size_t)pt*128 + m0 + mp]);
    sOD[prow][mp]   = b2f(a0[0]) + b2f(a1[0]);
    sOD[prow][mp+1] = b2f(a0[1]) + b2f(a1[1]);
  }
  __syncthreads();
  int wv2 = tid >> 6, lane = tid & 63;
  int qd = lane >> 4, mr = lane & 15;
  frag_cd acc[4] = {};
  #pragma unroll
  for (int k0=0;k0<128;k0+=32){
    frag_ab af = *reinterpret_cast<frag_ab*>(&sA[wv2*16+mr][k0+qd*8]);
    #pragma unroll
    for (int t=0;t<4;t++){
      frag_ab bfr = ld_frag_2xb64(&sBt[t*16+mr][k0+qd*8]);
      acc[t] = __builtin_amdgcn_mfma_f32_16x16x32_bf16(af, bfr, acc[t], 0, 0, 0);
    }
  }
  #pragma unroll
  for (int r=0;r<4;r++){
    int m = m0 + wv2*16 + qd*4 + r;
    float bias = pwb[m];
    float s = 0.f;
    #pragma unroll
    for (int t=0;t<4;t++){
      int p = p0 + t*16 + mr;
      float val = acc[t][r] + bias + sOD[t*16+mr][m - m0];
      fused[((size_t)b*128 + m)*LLEN + p] = val;
      s += val;
    }
    s += __shfl_xor(s, 1, 16);
    s += __shfl_xor(s, 2, 16);
    s += __shfl_xor(s, 4, 16);
    s += __shfl_xor(s, 8, 16);
    if (mr == 0) atomicAdd(&YMEAN[b*128 + m], s);
  }
}

// ---------------- final: compute gate per (b,c) in-block, out = fused*gate + x ----------------
__global__ void k_final_gate(const float* __restrict__ fused, const float* __restrict__ YMEAN,
                             const float* __restrict__ fc1, const float* __restrict__ fc2,
                             const float* __restrict__ x, float* __restrict__ out){
  int bc = blockIdx.y;           // 0..255
  int b = bc >> 7, c = bc & 127;
  __shared__ float ym[128], s1[32];
  __shared__ float gsh;
  int tid = threadIdx.x;
  if (tid < 128) ym[tid] = YMEAN[b*128 + tid] * (1.f/(float)LLEN);
  __syncthreads();
  if (tid < 32){
    float a = 0.f;
    for (int cc=0;cc<128;cc++) a += ym[cc]*fc1[tid*128+cc];
    s1[tid] = fmaxf(a, 0.f);
  }
  __syncthreads();
  if (tid == 0){
    float a = 0.f;
    #pragma unroll
    for (int j=0;j<32;j++) a += s1[j]*fc2[c*32+j];
    gsh = 1.f/(1.f+__expf(-a));
  }
  __syncthreads();
  float g = gsh;
  int p = blockIdx.x*256 + tid;
  if (p < LLEN){
    size_t i = (size_t)bc*LLEN + p;
    out[i] = fused[i]*g + x[i];
  }
}

extern "C" void kernel_launch(void* const* d_in, const int* in_sizes, int n_in,
                              void* d_out, int out_size, void* d_ws, size_t ws_size,
                              hipStream_t stream) {
  const float* x      = (const float*)d_in[0];
  const float* nhw    = (const float*)d_in[1];
  const float* nhb    = (const float*)d_in[2];
  const float* nvw    = (const float*)d_in[3];
  const float* nvb    = (const float*)d_in[4];
  const float* dww    = (const float*)d_in[5];
  const float* dwb    = (const float*)d_in[6];
  const float* pww    = (const float*)d_in[7];
  const float* pwb    = (const float*)d_in[8];
  const float* h_inw  = (const float*)d_in[9];
  const float* h_cw   = (const float*)d_in[10];
  const float* h_cb   = (const float*)d_in[11];
  const float* h_xw   = (const float*)d_in[12];
  const float* h_dtw  = (const float*)d_in[13];
  const float* h_dtb  = (const float*)d_in[14];
  const float* h_Al   = (const float*)d_in[15];
  const float* h_D    = (const float*)d_in[16];
  const float* h_ow   = (const float*)d_in[17];
  const float* v_inw  = (const float*)d_in[18];
  const float* v_cw   = (const float*)d_in[19];
  const float* v_cb   = (const float*)d_in[20];
  const float* v_xw   = (const float*)d_in[21];
  const float* v_dtw  = (const float*)d_in[22];
  const float* v_dtb  = (const float*)d_in[23];
  const float* v_Al   = (const float*)d_in[24];
  const float* v_D    = (const float*)d_in[25];
  const float* v_ow   = (const float*)d_in[26];
  const float* fc1    = (const float*)d_in[27];
  const float* fc2    = (const float*)d_in[28];

  float* FUSED = (float*)d_out;   // FUSED lives in d_out; k_final_gate is in-place elementwise
  float* out   = (float*)d_out;

  // Workspace layout (bytes), high-water ~35.3 MB. Stream-ordered-safe aliases:
  //  DT2 at base+0 (XLN under it dead after k_inproj); OD overlays DT2 (dead after k_scan3)
  //  YS overlays XI (dead after k_conv); Pbuf/Hbuf outside all aliases (read during scan3)
  char* base = (char*)d_ws;
  bf16*  XLN   = (bf16*)(base + 1605632);     // 3,211,264 B
  bf16*  DT2   = (bf16*)(base + 0);           // 6,422,528 B  [overlays XLN region; scan layout]
  bf16*  OD    = (bf16*)(base + 0);           // 3,211,264 B  [alias DT2; live after k_scan3]
  bf16*  XI    = (bf16*)(base + 6422528);     // 6,422,528 B
  bf16*  YS    = (bf16*)(base + 6422528);     // 6,422,528 B  [alias XI]
  bf16*  Z     = (bf16*)(base + 12845056);    // 6,422,528 B
  bf16*  XS2   = (bf16*)(base + 19267584);    // 6,422,528 B  [scan layout]
  float* Bf    = (float*)(base + 25690112);   //   802,816 B
  float* Cf    = (float*)(base + 26492928);   //   802,816 B
  float* Hbuf  = (float*)(base + 27295744);   // 3,211,264 B
  float* YMEAN = (float*)(base + 30507008);   //     1,024 B
  bf16*  TMP   = (bf16*)(base + 30508032);    // 1,605,632 B  (ends 32,113,664)
  float* Pbuf  = (float*)(base + 32113664);   // 3,211,264 B  (ends 35,324,928)

  k_front<<<dim3(1024 + 56*BATCH), dim3(256), 0, stream>>>(x, dww, dwb, TMP,
                                                           nhw, nhb, nvw, nvb, XLN, YMEAN);
  k_inproj<<<dim3(98,4,2), dim3(256), 0, stream>>>(XLN, h_inw, v_inw, XI, Z);
  k_conv<<<dim3(98,BATCH,2), dim3(256), 0, stream>>>(XI, h_cw, h_cb, v_cw, v_cb, XS2);
  k_dbl<<<dim3(196), dim3(256), 0, stream>>>(XS2, h_xw, v_xw, h_dtw, v_dtw, h_dtb, v_dtb,
                                             h_Al, v_Al, DT2, Bf, Cf, Pbuf, Hbuf);
  k_scan2<<<dim3(64), dim3(256), 0, stream>>>(Pbuf, Hbuf);
  k_scan3<<<dim3(NCHUNK,16,4), dim3(256), 0, stream>>>(DT2, XS2, Bf, Cf, h_Al, v_Al, Hbuf, YS);
  k_outgemm<<<dim3(196,2), dim3(256), 0, stream>>>(YS, XS2, Z, h_D, v_D, h_ow, v_ow, OD);
  k_pwcomb<<<dim3(49,2,BATCH), dim3(256), 0, stream>>>(TMP, pww, pwb, OD, FUSED, YMEAN);
  k_final_gate<<<dim3(13,256), dim3(256), 0, stream>>>(FUSED, YMEAN, fc1, fc2, x, out);
}

// Round 18
// 237.576 us; speedup vs baseline: 1.1062x; 1.0423x over previous
//
#include <hip/hip_runtime.h>
#include <hip/hip_bf16.h>

typedef __hip_bfloat16 bf16;
__device__ __forceinline__ float b2f(bf16 v){ return __bfloat162float(v); }
__device__ __forceinline__ bf16 f2b(float v){ return __float2bfloat16(v); }

typedef __attribute__((ext_vector_type(8))) short frag_ab;   // 8 bf16 (4 VGPRs)
typedef __attribute__((ext_vector_type(4))) float frag_cd;   // 4 fp32 acc
typedef __attribute__((ext_vector_type(4))) short short4v;   // 8B

__device__ __forceinline__ frag_ab ld_frag_2xb64(const bf16* p){
  union { frag_ab f; short4v h[2]; } u;
  u.h[0] = *reinterpret_cast<const short4v*>(p);
  u.h[1] = *reinterpret_cast<const short4v*>(p+4);
  return u.f;
}

#define LLEN 3136
#define BATCH 2
#define NCHUNK 49
#define LC 64

// ---------------- fused: dwconv3x3+gelu (blocks 0..1023) | LayerNorm (blocks 1024..1135) ----------------
__global__ void k_front(const float* __restrict__ x, const float* __restrict__ dww,
                        const float* __restrict__ dwb, bf16* __restrict__ tmp,
                        const float* nhw_, const float* nhb_, const float* nvw_,
                        const float* nvb_, bf16* __restrict__ xln,
                        float* __restrict__ YMEAN){
  int blk = blockIdx.x;
  int tid = threadIdx.x;
  if (blk < 1024){
    int bc = blk & 255;            // b*128 + c
    int seg = blk >> 8;
    int c = bc & 127;
    if (bc == 0 && seg == 0 && tid < 256) YMEAN[tid] = 0.f;
    const float* xp = x + (size_t)bc*LLEN;
    float w[9];
    #pragma unroll
    for (int i=0;i<9;i++) w[i] = dww[c*9+i];
    float bias = dwb[c];
    int pstart = seg * 784;
    for (int p = pstart + tid; p < pstart + 784; p += 256){
      int i = p/56, j = p%56;
      float acc = bias;
      #pragma unroll
      for (int a=0;a<3;a++){
        int ii = i + a - 1;
        if (ii < 0 || ii >= 56) continue;
        #pragma unroll
        for (int bb=0;bb<3;bb++){
          int jj = j + bb - 1;
          if (jj < 0 || jj >= 56) continue;
          acc += w[a*3+bb] * xp[ii*56+jj];
        }
      }
      float g = 0.5f*acc*(1.0f + erff(acc*0.70710678118654752f));
      tmp[(size_t)bc*LLEN + p] = f2b(g);
    }
  } else {
    int idx2 = blk - 1024;         // 0..111
    int h = idx2 % 56, b = idx2 / 56;
    __shared__ float sx[128][57];
    __shared__ float smean[56], srstd[56];
    __shared__ float wh[128], bh[128], wv_[128], bv_[128];
    if (tid < 128){ wh[tid]=nhw_[tid]; bh[tid]=nhb_[tid];
                    wv_[tid]=nvw_[tid]; bv_[tid]=nvb_[tid]; }
    for (int idx = tid; idx < 128*56; idx += 256){
      int c = idx / 56, w = idx % 56;
      sx[c][w] = x[((size_t)(b*128+c))*LLEN + h*56 + w];
    }
    __syncthreads();
    if (tid < 56){
      float s=0.f, s2=0.f;
      for (int c=0;c<128;c++){ float v = sx[c][tid]; s+=v; s2+=v*v; }
      float m = s*(1.f/128.f);
      float var = s2*(1.f/128.f) - m*m;
      smean[tid]=m; srstd[tid]=rsqrtf(var+1e-5f);
    }
    __syncthreads();
    bf16* outh = xln;
    bf16* outv = xln + (size_t)BATCH*LLEN*128;
    for (int idx = tid; idx < 56*128; idx += 256){
      int w = idx >> 7, c = idx & 127;
      float v = (sx[c][w]-smean[w])*srstd[w];
      outh[((size_t)b*LLEN + h*56 + w)*128 + c] = f2b(v*wh[c]+bh[c]);
      outv[((size_t)b*LLEN + w*56 + h)*128 + c] = f2b(v*wv_[c]+bv_[c]);
    }
  }
}

// ---------------- in_proj GEMM (MFMA bf16): 64-row tile, 2 n-tiles per block (A staged once) ----------------
__global__ void k_inproj(const bf16* __restrict__ xln, const float* __restrict__ hw,
                         const float* __restrict__ vw, bf16* __restrict__ XI, bf16* __restrict__ Z){
  int dir = blockIdx.z;
  const bf16* A = xln + (size_t)dir*BATCH*LLEN*128;
  const float* W = dir ? vw : hw;
  int m0 = blockIdx.x*64;
  int npair = blockIdx.y*128;     // covers n0 = npair, npair+64 (same XI/Z half)
  __shared__ __align__(16) bf16 sA[64][136];
  __shared__ __align__(16) bf16 sW[64][136];
  int tid = threadIdx.x;
  #pragma unroll
  for (int r=0;r<4;r++){
    int idx = tid + r*256;
    int row = idx >> 4, c8 = (idx & 15)*8;
    *reinterpret_cast<float4*>(&sA[row][c8]) =
        *reinterpret_cast<const float4*>(&A[(size_t)(m0+row)*128 + c8]);
  }
  int wv2 = tid >> 6, lane = tid & 63;
  int qd = lane >> 4, mr = lane & 15;
  bf16* dst = (npair < 256) ? XI : Z;
  int nbase0 = npair & 255;
  size_t dslab = (size_t)dir*BATCH*LLEN*256;
  #pragma unroll
  for (int nt=0; nt<2; nt++){
    int n0 = npair + nt*64;
    __syncthreads();
    #pragma unroll
    for (int r=0;r<8;r++){
      int idx = tid + r*256;
      int row = idx >> 5, c4 = (idx & 31)*4;
      float4 w4 = *reinterpret_cast<const float4*>(&W[(size_t)(n0+row)*128 + c4]);
      bf16 t4[4] = {f2b(w4.x), f2b(w4.y), f2b(w4.z), f2b(w4.w)};
      *reinterpret_cast<double*>(&sW[row][c4]) = *reinterpret_cast<double*>(t4);
    }
    __syncthreads();
    frag_cd acc[4] = {};
    #pragma unroll
    for (int k0=0;k0<128;k0+=32){
      frag_ab af = *reinterpret_cast<frag_ab*>(&sA[wv2*16+mr][k0+qd*8]);
      #pragma unroll
      for (int t=0;t<4;t++){
        frag_ab bfr = *reinterpret_cast<frag_ab*>(&sW[t*16+mr][k0+qd*8]);
        acc[t] = __builtin_amdgcn_mfma_f32_16x16x32_bf16(af, bfr, acc[t], 0, 0, 0);
      }
    }
    int nb = nbase0 + nt*64;
    #pragma unroll
    for (int t=0;t<4;t++)
      #pragma unroll
      for (int r=0;r<4;r++){
        int row = m0 + wv2*16 + qd*4 + r;
        int col = nb + t*16 + mr;
        dst[dslab + (size_t)row*256 + col] = f2b(acc[t][r]);
      }
  }
}

// ---------------- causal depthwise conv1d(k=4) + silu; writes XS2 (scan layout) only ----------------
__global__ void k_conv(const bf16* __restrict__ XI, const float* hw, const float* hb,
                       const float* vw, const float* vb, bf16* __restrict__ XS2){
  int dir = blockIdx.z;
  int b = blockIdx.y;
  int bd = dir*BATCH + b;
  int l0 = blockIdx.x * 32;
  const bf16* XId = XI + (size_t)bd*LLEN*256;
  const float* cw = dir ? vw : hw;
  const float* cb = dir ? vb : hb;
  __shared__ float sxi[35][256];
  int tid = threadIdx.x;
  for (int r = 0; r < 35; r++){
    int l = l0 - 3 + r;
    sxi[r][tid] = (l >= 0) ? b2f(XId[(size_t)l*256 + tid]) : 0.f;
  }
  __syncthreads();
  float w0=cw[tid*4], w1=cw[tid*4+1], w2=cw[tid*4+2], w3=cw[tid*4+3];
  float bias = cb[tid];
  size_t x2base = ((size_t)bd*16 + (tid>>4))*LLEN;
  int c16 = tid & 15;
  for (int ll=0; ll<32; ll++){
    float acc = bias + w0*sxi[ll][tid] + w1*sxi[ll+1][tid] + w2*sxi[ll+2][tid] + w3*sxi[ll+3][tid];
    float s = acc / (1.f + __expf(-acc));
    XS2[(x2base + l0 + ll)*16 + c16] = f2b(s);
  }
}

// ---------------- xproj (MFMA): DBL tile -> dt(softplus)->DT2, B/C extract (scan1 un-fused) ----------------
__global__ void k_dbl(const bf16* __restrict__ XS2, const float* __restrict__ hx,
                      const float* __restrict__ vx,
                      const float* hdw, const float* vdw, const float* hdb, const float* vdb,
                      bf16* __restrict__ DT2, float* __restrict__ Bf, float* __restrict__ Cf){
  int m0 = blockIdx.x*64;                      // 196 tiles; never crosses bd boundary
  int bd = m0 / LLEN;
  int l0m = m0 % LLEN;
  int dirq = bd >> 1;
  const float* W = dirq ? vx : hx;
  __shared__ __align__(16) bf16 sA[64][264];   // 33.8 KB
  __shared__ __align__(16) bf16 sW[48][264];   // 25.3 KB (rows 40..47 zero)
  __shared__ float sdbl[64][49];               // 12.5 KB
  int tid = threadIdx.x;
  #pragma unroll
  for (int r=0;r<8;r++){
    int idx = tid + r*256;
    int row = idx >> 5, c8 = (idx & 31)*8;
    size_t src = (((size_t)bd*16 + (c8>>4))*LLEN + l0m + row)*16 + (c8&15);
    *reinterpret_cast<float4*>(&sA[row][c8]) =
        *reinterpret_cast<const float4*>(&XS2[src]);
  }
  #pragma unroll
  for (int r=0;r<12;r++){
    int idx = tid + r*256;                     // 3072 = 48*64 chunks of 4
    int row = idx >> 6, c4 = (idx & 63)*4;
    bf16 t4[4] = {f2b(0.f), f2b(0.f), f2b(0.f), f2b(0.f)};
    if (row < 40){
      float4 w4 = *reinterpret_cast<const float4*>(&W[(size_t)row*256 + c4]);
      t4[0]=f2b(w4.x); t4[1]=f2b(w4.y); t4[2]=f2b(w4.z); t4[3]=f2b(w4.w);
    }
    *reinterpret_cast<double*>(&sW[row][c4]) = *reinterpret_cast<double*>(t4);
  }
  __syncthreads();
  int wv2 = tid >> 6, lane = tid & 63;
  int qd = lane >> 4, mr = lane & 15;
  frag_cd acc[3] = {};
  #pragma unroll
  for (int k0=0;k0<256;k0+=32){
    frag_ab af = *reinterpret_cast<frag_ab*>(&sA[wv2*16+mr][k0+qd*8]);
    #pragma unroll
    for (int t=0;t<3;t++){
      frag_ab bfr = *reinterpret_cast<frag_ab*>(&sW[t*16+mr][k0+qd*8]);
      acc[t] = __builtin_amdgcn_mfma_f32_16x16x32_bf16(af, bfr, acc[t], 0, 0, 0);
    }
  }
  #pragma unroll
  for (int t=0;t<3;t++)
    #pragma unroll
    for (int r=0;r<4;r++){
      int col = t*16 + mr;
      if (col < 40) sdbl[wv2*16 + qd*4 + r][col] = acc[t][r];
    }
  __syncthreads();
  // dt = softplus(dbl[:8] @ dtw^T + dtb) -> DT2 (scan layout)
  const float* dtw = dirq ? vdw : hdw;
  const float* dtb = dirq ? vdb : hdb;
  float w8[8];
  #pragma unroll
  for (int r=0;r<8;r++) w8[r] = dtw[tid*8+r];
  float biasv = dtb[tid];
  size_t d2base = ((size_t)bd*16 + (tid>>4))*LLEN + l0m;
  int c16 = tid & 15;
  for (int row=0; row<64; row++){
    float a = biasv;
    #pragma unroll
    for (int r=0;r<8;r++) a += sdbl[row][r]*w8[r];
    float sv = (a > 20.f) ? a : __logf(1.f + __expf(a));
    DT2[(d2base + row)*16 + c16] = f2b(sv);
  }
  #pragma unroll
  for (int r=0;r<8;r++){
    int idx = tid + r*256;                     // 2048 = 64 rows * 32 vals
    int row = idx >> 5, o = idx & 31;
    float v = sdbl[row][8+o];
    size_t rr = (size_t)(m0+row)*16;
    if (o < 16) Bf[rr + o] = v;
    else        Cf[rr + (o-16)] = v;
  }
}

// ---------------- scan pass 1: local chunk scan (high parallelism), P & h_end ----------------
__global__ void k_scan1(const bf16* __restrict__ DT2, const bf16* __restrict__ XS2,
                        const float* __restrict__ Bc, const float* hA, const float* vA,
                        float* __restrict__ Pbuf, float* __restrict__ Hbuf){
  int bd = blockIdx.z;           // dir*2+b
  int g  = blockIdx.y;           // channel group 0..15
  int ck = blockIdx.x;           // chunk 0..48
  int l0 = ck*LC;
  const float* Bd = Bc + (size_t)bd*LLEN*16;
  const float* Alog = (bd >> 1) ? vA : hA;
  int tid = threadIdx.x;
  int dl = tid >> 4, n = tid & 15;
  float A = -__expf(Alog[(g*16+dl)*16+n]);
  __shared__ float sdt[LC][16], sxs[LC][16], sB[LC][16];
  size_t base2 = (((size_t)bd*16 + g)*LLEN + l0)*16;
  #pragma unroll
  for (int r=0;r<4;r++){
    int idx = tid + r*256;
    sdt[idx>>4][idx&15] = b2f(DT2[base2 + idx]);
    sxs[idx>>4][idx&15] = b2f(XS2[base2 + idx]);
    (&sB[0][0])[idx] = Bd[(size_t)l0*16 + idx];
  }
  __syncthreads();
  float h = 0.f, P = 1.f;
  #pragma unroll 8
  for (int i=0;i<LC;i++){
    float a = sdt[i][dl];
    float u = sxs[i][dl];
    float dA = __expf(a * A);
    h = dA*h + (a*u)*sB[i][n];
    P *= dA;
  }
  size_t sidx = (((size_t)bd*16 + g)*NCHUNK + ck)*256 + tid;
  Pbuf[sidx] = P;
  Hbuf[sidx] = h;
}

// ---------------- pass 2: sequential combine over chunks (in-place h_end -> h_init) ----------------
__global__ void k_scan2(const float* __restrict__ Pbuf, float* __restrict__ Hbuf){
  int q = blockIdx.x;            // bd*16+g, 0..63
  int tid = threadIdx.x;
  float carry = 0.f;
  for (int k=0;k<NCHUNK;k++){
    size_t idx = ((size_t)q*NCHUNK + k)*256 + tid;
    float Pv = Pbuf[idx];
    float He = Hbuf[idx];
    Hbuf[idx] = carry;           // h_init for chunk k
    carry = Pv*carry + He;
  }
}

// ---------------- pass 3: local scan from h_init, swizzled LDS reduce (bank-conflict-free) ----------------
__global__ void k_scan3(const bf16* __restrict__ DT2, const bf16* __restrict__ XS2,
                        const float* __restrict__ Bc, const float* __restrict__ Cc,
                        const float* hA, const float* vA,
                        const float* __restrict__ Hbuf, bf16* __restrict__ ys){
  int bd = blockIdx.z;
  int g  = blockIdx.y;
  int ck = blockIdx.x;
  int l0 = ck*LC;
  const float* Bd = Bc + (size_t)bd*LLEN*16;
  const float* Cd = Cc + (size_t)bd*LLEN*16;
  bf16* yd = ys + (size_t)bd*LLEN*256;
  const float* Alog = (bd >> 1) ? vA : hA;
  int tid = threadIdx.x;
  int dl = tid >> 4, n = tid & 15;
  float A = -__expf(Alog[(g*16+dl)*16+n]);
  __shared__ float sdt[LC][16], sxs[LC][16], sB[LC][16], sC[LC][16];
  __shared__ float sp2[16][272];   // swizzled: element (dl,n) at dl*17+n -> <=2-way banks
  size_t base2 = (((size_t)bd*16 + g)*LLEN + l0)*16;
  #pragma unroll
  for (int r=0;r<4;r++){
    int idx = tid + r*256;
    sdt[idx>>4][idx&15] = b2f(DT2[base2 + idx]);
    sxs[idx>>4][idx&15] = b2f(XS2[base2 + idx]);
    (&sB[0][0])[idx] = Bd[(size_t)l0*16 + idx];
    (&sC[0][0])[idx] = Cd[(size_t)l0*16 + idx];
  }
  size_t sidx = (((size_t)bd*16 + g)*NCHUNK + ck)*256 + tid;
  float h = Hbuf[sidx];
  __syncthreads();
  int swz = dl*17 + n;           // write offset within sp2 row
  int i_local = tid >> 4;        // reduce-phase: step within subchunk
  int c16 = tid & 15;            // reduce-phase: channel-in-group
  int rbase = c16*17;            // read base within sp2 row
  for (int i0=0; i0<LC; i0+=16){
    #pragma unroll
    for (int ii=0;ii<16;ii++){
      int i = i0 + ii;
      float a = sdt[i][dl];
      float u = sxs[i][dl];
      float dA = __expf(a * A);
      h = dA*h + (a*u)*sB[i][n];
      sp2[ii][swz] = h * sC[i][n];
    }
    __syncthreads();
    const float* row = &sp2[i_local][rbase];
    float s = 0.f;
    #pragma unroll
    for (int k=0;k<16;k++) s += row[k];
    yd[(size_t)(l0+i0+i_local)*256 + g*16 + c16] = f2b(s);
    __syncthreads();
  }
}

// ---------------- out_proj GEMM (MFMA bf16): 32-row tiles, both n-halves, YF staged once ----------------
__global__ void k_outgemm(const bf16* __restrict__ ys, const bf16* __restrict__ XS2,
                          const bf16* __restrict__ Z, const float* __restrict__ hD,
                          const float* __restrict__ vD, const float* __restrict__ how,
                          const float* __restrict__ vow, bf16* __restrict__ OD){
  int dir = blockIdx.y;
  size_t slab = (size_t)dir*BATCH*LLEN*256;
  const float* W = dir ? vow : how;
  const float* Dw = dir ? vD : hD;
  bf16* od = OD + (size_t)dir*BATCH*LLEN*128;
  int m0 = blockIdx.x*32;        // 196 m-tiles per dir; 3136 % 32 == 0
  int bd = dir*2 + m0/LLEN;
  int lbase = m0 % LLEN;
  __shared__ __align__(16) bf16 sA[32][264];   // 16.9 KB
  __shared__ __align__(16) bf16 sW[64][264];   // 33.8 KB
  int tid = threadIdx.x;
  #pragma unroll
  for (int r=0;r<4;r++){
    int idx = tid + r*256;                     // 1024 chunks of 8
    int row = idx >> 5, c8 = (idx & 31)*8;
    size_t e = slab + (size_t)(m0+row)*256 + c8;
    size_t e2 = (((size_t)bd*16 + (c8>>4))*LLEN + lbase + row)*16 + (c8&15);
    bf16 yb[8], xb[8], zb[8], ob[8];
    *reinterpret_cast<float4*>(yb) = *reinterpret_cast<const float4*>(&ys[e]);
    *reinterpret_cast<float4*>(xb) = *reinterpret_cast<const float4*>(&XS2[e2]);
    *reinterpret_cast<float4*>(zb) = *reinterpret_cast<const float4*>(&Z[e]);
    #pragma unroll
    for (int j=0;j<8;j++){
      float Dv = Dw[c8 + j];
      float yv = b2f(yb[j]) + b2f(xb[j])*Dv;
      float zv = b2f(zb[j]);
      ob[j] = f2b(yv * (zv/(1.f+__expf(-zv))));
    }
    *reinterpret_cast<float4*>(&sA[row][c8]) = *reinterpret_cast<float4*>(ob);
  }
  int wv2 = tid >> 6, lane = tid & 63;
  int qd = lane >> 4, mr = lane & 15;
  int msub = wv2 & 1, tpair = (wv2 >> 1)*2;
  #pragma unroll
  for (int nh=0; nh<2; nh++){
    int n0 = nh*64;
    __syncthreads();
    #pragma unroll
    for (int r=0;r<16;r++){
      int idx = tid + r*256;                   // 4096 chunks of 4
      int row = idx >> 6, c4 = (idx & 63)*4;
      float4 w4 = *reinterpret_cast<const float4*>(&W[(size_t)(n0+row)*256 + c4]);
      bf16 t4[4] = {f2b(w4.x), f2b(w4.y), f2b(w4.z), f2b(w4.w)};
      *reinterpret_cast<double*>(&sW[row][c4]) = *reinterpret_cast<double*>(t4);
    }
    __syncthreads();
    frag_cd acc[2] = {};
    #pragma unroll
    for (int k0=0;k0<256;k0+=32){
      frag_ab af = *reinterpret_cast<frag_ab*>(&sA[msub*16+mr][k0+qd*8]);
      #pragma unroll
      for (int i=0;i<2;i++){
        frag_ab bfr = *reinterpret_cast<frag_ab*>(&sW[(tpair+i)*16+mr][k0+qd*8]);
        acc[i] = __builtin_amdgcn_mfma_f32_16x16x32_bf16(af, bfr, acc[i], 0, 0, 0);
      }
    }
    #pragma unroll
    for (int i=0;i<2;i++)
      #pragma unroll
      for (int r=0;r<4;r++){
        int row = m0 + msub*16 + qd*4 + r;
        int col = n0 + (tpair+i)*16 + mr;
        od[(size_t)row*128 + col] = f2b(acc[i][r]);
      }
  }
}

// ---------------- pw conv (MFMA) + combine OD + OD^T + YMEAN partials, single FUSED write ----------------
__global__ void k_pwcomb(const bf16* __restrict__ tmp, const float* __restrict__ pww,
                         const float* __restrict__ pwb, const bf16* __restrict__ OD,
                         float* __restrict__ fused, float* __restrict__ YMEAN){
  int p0 = blockIdx.x * 64;       // 49 p-tiles
  int m0 = blockIdx.y * 64;       // 2 out-channel halves
  int b  = blockIdx.z;
  const bf16* T = tmp + (size_t)b*128*LLEN;
  const bf16* od0 = OD + (size_t)b*LLEN*128;
  const bf16* od1 = OD + (size_t)(BATCH + b)*LLEN*128;
  __shared__ __align__(16) bf16 sA[64][136];    // pww rows m0.., k=c (bf16)
  __shared__ __align__(16) bf16 sBt[64][132];   // [p][c] transposed tmp tile
  __shared__ float sOD[64][65];                 // [p][m] od0 + od1^T
  int tid = threadIdx.x;
  #pragma unroll
  for (int r=0;r<8;r++){
    int idx = tid + r*256;
    int row = idx >> 5, c4 = (idx & 31)*4;
    float4 w4 = *reinterpret_cast<const float4*>(&pww[(size_t)(m0+row)*128 + c4]);
    bf16 t4[4] = {f2b(w4.x), f2b(w4.y), f2b(w4.z), f2b(w4.w)};
    *reinterpret_cast<double*>(&sA[row][c4]) = *reinterpret_cast<double*>(t4);
  }
  #pragma unroll
  for (int r=0;r<8;r++){
    int idx = tid + r*256;
    int c = idx >> 4, p4 = (idx & 15)*4;
    union { double d; bf16 v[4]; } u;
    u.d = *reinterpret_cast<const double*>(&T[(size_t)c*LLEN + p0 + p4]);
    #pragma unroll
    for (int j=0;j<4;j++) sBt[p4+j][c] = u.v[j];
  }
  #pragma unroll
  for (int r=0;r<8;r++){
    int idx = tid + r*256;       // 2048 = 64 p-rows * 32 m-pairs
    int prow = idx >> 5, mp = (idx & 31)*2;
    int p = p0 + prow;
    int pi = p/56, pj = p%56;
    int pt = pj*56 + pi;
    bf16 a0[2], a1[2];
    *reinterpret_cast<float*>(a0) = *reinterpret_cast<const float*>(&od0[(size_t)p*128 + m0 + mp]);
    *reinterpret_cast<float*>(a1) = *reinterpret_cast<const float*>(&od1[(size_t)pt*128 + m0 + mp]);
    sOD[prow][mp]   = b2f(a0[0]) + b2f(a1[0]);
    sOD[prow][mp+1] = b2f(a0[1]) + b2f(a1[1]);
  }
  __syncthreads();
  int wv2 = tid >> 6, lane = tid & 63;
  int qd = lane >> 4, mr = lane & 15;
  frag_cd acc[4] = {};
  #pragma unroll
  for (int k0=0;k0<128;k0+=32){
    frag_ab af = *reinterpret_cast<frag_ab*>(&sA[wv2*16+mr][k0+qd*8]);
    #pragma unroll
    for (int t=0;t<4;t++){
      frag_ab bfr = ld_frag_2xb64(&sBt[t*16+mr][k0+qd*8]);
      acc[t] = __builtin_amdgcn_mfma_f32_16x16x32_bf16(af, bfr, acc[t], 0, 0, 0);
    }
  }
  #pragma unroll
  for (int r=0;r<4;r++){
    int m = m0 + wv2*16 + qd*4 + r;
    float bias = pwb[m];
    float s = 0.f;
    #pragma unroll
    for (int t=0;t<4;t++){
      int p = p0 + t*16 + mr;
      float val = acc[t][r] + bias + sOD[t*16+mr][m - m0];
      fused[((size_t)b*128 + m)*LLEN + p] = val;
      s += val;
    }
    s += __shfl_xor(s, 1, 16);
    s += __shfl_xor(s, 2, 16);
    s += __shfl_xor(s, 4, 16);
    s += __shfl_xor(s, 8, 16);
    if (mr == 0) atomicAdd(&YMEAN[b*128 + m], s);
  }
}

// ---------------- final: compute gate per (b,c) in-block, out = fused*gate + x ----------------
__global__ void k_final_gate(const float* __restrict__ fused, const float* __restrict__ YMEAN,
                             const float* __restrict__ fc1, const float* __restrict__ fc2,
                             const float* __restrict__ x, float* __restrict__ out){
  int bc = blockIdx.y;           // 0..255
  int b = bc >> 7, c = bc & 127;
  __shared__ float ym[128], s1[32];
  __shared__ float gsh;
  int tid = threadIdx.x;
  if (tid < 128) ym[tid] = YMEAN[b*128 + tid] * (1.f/(float)LLEN);
  __syncthreads();
  if (tid < 32){
    float a = 0.f;
    for (int cc=0;cc<128;cc++) a += ym[cc]*fc1[tid*128+cc];
    s1[tid] = fmaxf(a, 0.f);
  }
  __syncthreads();
  if (tid == 0){
    float a = 0.f;
    #pragma unroll
    for (int j=0;j<32;j++) a += s1[j]*fc2[c*32+j];
    gsh = 1.f/(1.f+__expf(-a));
  }
  __syncthreads();
  float g = gsh;
  int p = blockIdx.x*256 + tid;
  if (p < LLEN){
    size_t i = (size_t)bc*LLEN + p;
    out[i] = fused[i]*g + x[i];
  }
}

extern "C" void kernel_launch(void* const* d_in, const int* in_sizes, int n_in,
                              void* d_out, int out_size, void* d_ws, size_t ws_size,
                              hipStream_t stream) {
  const float* x      = (const float*)d_in[0];
  const float* nhw    = (const float*)d_in[1];
  const float* nhb    = (const float*)d_in[2];
  const float* nvw    = (const float*)d_in[3];
  const float* nvb    = (const float*)d_in[4];
  const float* dww    = (const float*)d_in[5];
  const float* dwb    = (const float*)d_in[6];
  const float* pww    = (const float*)d_in[7];
  const float* pwb    = (const float*)d_in[8];
  const float* h_inw  = (const float*)d_in[9];
  const float* h_cw   = (const float*)d_in[10];
  const float* h_cb   = (const float*)d_in[11];
  const float* h_xw   = (const float*)d_in[12];
  const float* h_dtw  = (const float*)d_in[13];
  const float* h_dtb  = (const float*)d_in[14];
  const float* h_Al   = (const float*)d_in[15];
  const float* h_D    = (const float*)d_in[16];
  const float* h_ow   = (const float*)d_in[17];
  const float* v_inw  = (const float*)d_in[18];
  const float* v_cw   = (const float*)d_in[19];
  const float* v_cb   = (const float*)d_in[20];
  const float* v_xw   = (const float*)d_in[21];
  const float* v_dtw  = (const float*)d_in[22];
  const float* v_dtb  = (const float*)d_in[23];
  const float* v_Al   = (const float*)d_in[24];
  const float* v_D    = (const float*)d_in[25];
  const float* v_ow   = (const float*)d_in[26];
  const float* fc1    = (const float*)d_in[27];
  const float* fc2    = (const float*)d_in[28];

  float* FUSED = (float*)d_out;   // FUSED lives in d_out; k_final_gate is in-place elementwise
  float* out   = (float*)d_out;

  // Workspace layout (bytes), high-water ~35.3 MB. Stream-ordered-safe aliases:
  //  DT2 at base+0 (XLN under it dead after k_inproj); OD overlays DT2 (dead after k_scan3)
  //  YS overlays XI (dead after k_conv); Pbuf/Hbuf outside all aliases
  char* base = (char*)d_ws;
  bf16*  XLN   = (bf16*)(base + 1605632);     // 3,211,264 B
  bf16*  DT2   = (bf16*)(base + 0);           // 6,422,528 B  [overlays XLN region; scan layout]
  bf16*  OD    = (bf16*)(base + 0);           // 3,211,264 B  [alias DT2; live after k_scan3]
  bf16*  XI    = (bf16*)(base + 6422528);     // 6,422,528 B
  bf16*  YS    = (bf16*)(base + 6422528);     // 6,422,528 B  [alias XI]
  bf16*  Z     = (bf16*)(base + 12845056);    // 6,422,528 B
  bf16*  XS2   = (bf16*)(base + 19267584);    // 6,422,528 B  [scan layout]
  float* Bf    = (float*)(base + 25690112);   //   802,816 B
  float* Cf    = (float*)(base + 26492928);   //   802,816 B
  float* Hbuf  = (float*)(base + 27295744);   // 3,211,264 B
  float* YMEAN = (float*)(base + 30507008);   //     1,024 B
  bf16*  TMP   = (bf16*)(base + 30508032);    // 1,605,632 B  (ends 32,113,664)
  float* Pbuf  = (float*)(base + 32113664);   // 3,211,264 B  (ends 35,324,928)

  k_front<<<dim3(1024 + 56*BATCH), dim3(256), 0, stream>>>(x, dww, dwb, TMP,
                                                           nhw, nhb, nvw, nvb, XLN, YMEAN);
  k_inproj<<<dim3(98,4,2), dim3(256), 0, stream>>>(XLN, h_inw, v_inw, XI, Z);
  k_conv<<<dim3(98,BATCH,2), dim3(256), 0, stream>>>(XI, h_cw, h_cb, v_cw, v_cb, XS2);
  k_dbl<<<dim3(196), dim3(256), 0, stream>>>(XS2, h_xw, v_xw, h_dtw, v_dtw, h_dtb, v_dtb,
                                             DT2, Bf, Cf);
  k_scan1<<<dim3(NCHUNK,16,4), dim3(256), 0, stream>>>(DT2, XS2, Bf, h_Al, v_Al, Pbuf, Hbuf);
  k_scan2<<<dim3(64), dim3(256), 0, stream>>>(Pbuf, Hbuf);
  k_scan3<<<dim3(NCHUNK,16,4), dim3(256), 0, stream>>>(DT2, XS2, Bf, Cf, h_Al, v_Al, Hbuf, YS);
  k_outgemm<<<dim3(196,2), dim3(256), 0, stream>>>(YS, XS2, Z, h_D, v_D, h_ow, v_ow, OD);
  k_pwcomb<<<dim3(49,2,BATCH), dim3(256), 0, stream>>>(TMP, pww, pwb, OD, FUSED, YMEAN);
  k_final_gate<<<dim3(13,256), dim3(256), 0, stream>>>(FUSED, YMEAN, fc1, fc2, x, out);
}